// Round 14
// baseline (211.075 us; speedup 1.0000x reference)
//
#include <hip/hip_runtime.h>
#include <hip/hip_bf16.h>

// out[m,b,:] = kv[m,b,:] @ W + bo + query[b,:],  W = (Wo@Wv) row o, col d
// (softmax over size-1 axis == 1 -> ones; q/k/Wq/Wk dead). f32 output.
// K1: Cw = Wo@Wv, MFMA bf16, 64x64 tiles, 256 blocks (~4us, proven r9).
// K2: T3-minimum pipeline: double-buffered LDS, stage(kt+1) issued BEFORE
//     compute(kt), ONE __syncthreads per K-step (implicit drain = race-free).
//     B-tile XOR swizzle chunk^=(row>>1)&3 both-sides kills the measured
//     8-way conflict (16.8M cycles, r13). A swizzle + 64x128 shape + 4
//     blocks/CU occupancy setup proven r13. XCD swizzle proven r8.

typedef __attribute__((ext_vector_type(4))) float f32x4;
typedef __attribute__((ext_vector_type(8))) short short8;

#define D_MODEL 1024
#define BATCH   4096
#define M_ROWS  32768   // 8 * 4096

__device__ __forceinline__ short f2bf(float f) {
    union { float f; unsigned u; } x; x.f = f;
    unsigned r = (x.u + 0x7fffu + ((x.u >> 16) & 1u)) >> 16;   // RNE
    return (short)r;
}

__device__ __forceinline__ unsigned bfpk(float lo, float hi) {
    __hip_bfloat162 h = __float22bfloat162_rn(make_float2(lo, hi));  // v_cvt_pk_bf16_f32
    unsigned u; __builtin_memcpy(&u, &h, 4); return u;
}

__device__ __forceinline__ short8 cvt8(float4 a, float4 b) {
    union { unsigned u[4]; short8 s; } r;
    r.u[0] = bfpk(a.x, a.y);
    r.u[1] = bfpk(a.z, a.w);
    r.u[2] = bfpk(b.x, b.y);
    r.u[3] = bfpk(b.z, b.w);
    return r.s;
}

// ---------------- Kernel 1: fuse weights Cw = Wo @ Wv (bf16, MFMA, 64x64) ----------------
__global__ __launch_bounds__(256) void fuse_w_kernel(
        const float* __restrict__ Wo, const float* __restrict__ Wv,
        short* __restrict__ Cw) {
    __shared__ __align__(16) short Ash[64][32];   // Wo tile  [o][e]
    __shared__ __align__(16) short Bsh[64][32];   // Wv tile transposed: [d][e]
    const int t = threadIdx.x;
    const int lane = t & 63;
    const int w = t >> 6;
    const int wr = w >> 1, wc = w & 1;
    const int brow = blockIdx.y * 64;   // o
    const int bcol = blockIdx.x * 64;   // d

    f32x4 acc[2][2];
#pragma unroll
    for (int m = 0; m < 2; ++m)
#pragma unroll
        for (int n = 0; n < 2; ++n) acc[m][n] = (f32x4)(0.0f);

    for (int kt = 0; kt < 32; ++kt) {
        const float* ga = Wo + (size_t)(brow + (t >> 2)) * D_MODEL + kt * 32 + (t & 3) * 8;
        float4 a0 = *(const float4*)ga;
        float4 a1 = *(const float4*)(ga + 4);
        float4 bv[2];
#pragma unroll
        for (int j = 0; j < 2; ++j) {
            int lin = j * 256 + t;
            int e = lin >> 4, c4 = lin & 15;
            bv[j] = *(const float4*)(Wv + (size_t)(kt * 32 + e) * D_MODEL + bcol + c4 * 4);
        }
        *reinterpret_cast<short8*>(&Ash[t >> 2][(t & 3) * 8]) = cvt8(a0, a1);
#pragma unroll
        for (int j = 0; j < 2; ++j) {
            int lin = j * 256 + t;
            int e = lin >> 4, c4 = lin & 15;
            int d = c4 * 4;
            Bsh[d + 0][e] = f2bf(bv[j].x);
            Bsh[d + 1][e] = f2bf(bv[j].y);
            Bsh[d + 2][e] = f2bf(bv[j].z);
            Bsh[d + 3][e] = f2bf(bv[j].w);
        }
        __syncthreads();
        {
            const int r = lane & 15, q = lane >> 4;
            short8 af[2], bfr[2];
#pragma unroll
            for (int m = 0; m < 2; ++m)
                af[m] = *reinterpret_cast<const short8*>(&Ash[wr * 32 + m * 16 + r][q * 8]);
#pragma unroll
            for (int n = 0; n < 2; ++n)
                bfr[n] = *reinterpret_cast<const short8*>(&Bsh[wc * 32 + n * 16 + r][q * 8]);
#pragma unroll
            for (int m = 0; m < 2; ++m)
#pragma unroll
                for (int n = 0; n < 2; ++n)
                    acc[m][n] = __builtin_amdgcn_mfma_f32_16x16x32_bf16(
                        af[m], bfr[n], acc[m][n], 0, 0, 0);
        }
        __syncthreads();
    }

    const int r = lane & 15, q = lane >> 4;
#pragma unroll
    for (int m = 0; m < 2; ++m)
#pragma unroll
        for (int n = 0; n < 2; ++n)
#pragma unroll
            for (int j = 0; j < 4; ++j) {
                int o = brow + wr * 32 + m * 16 + q * 4 + j;     // C/D: row=(l>>4)*4+j
                int d = bcol + wc * 32 + n * 16 + r;             //      col=l&15
                Cw[(size_t)o * D_MODEL + d] = f2bf(acc[m][n][j]);
            }
}

// ---------------- Kernel 2: out = kv @ Cw.T + bo + query — dbuf 1-barrier pipeline ----------------
__global__ __launch_bounds__(256, 4) void attn_gemm_kernel(
        const float* __restrict__ kv, const float* __restrict__ query,
        const short* __restrict__ Cw, const float* __restrict__ bo,
        float* __restrict__ out) {
    __shared__ __align__(16) float Afs[2][64][32];    // kv tile f32, swizzled (2x8 KB)
    __shared__ __align__(16) short Bsh[2][128][32];   // Cw tile bf16, swizzled (2x8 KB)
    const int t = threadIdx.x;
    const int lane = t & 63;
    const int w = t >> 6;
    const int wr = w >> 1, wc = w & 1;
    const int r = lane & 15, q = lane >> 4;

    // XCD swizzle: XCD = L % 8; the 8 o-tiles of one row-tile share an XCD
    // -> kv L2-reused 8x (proven r8: FETCH 574->141 MB).
    const int L = blockIdx.x;
    const int x = L & 7, j5 = L >> 3;
    const int bx = j5 & 7;                   // o-tile (0..7)
    const int rt = (j5 >> 3) * 8 + x;        // row-tile (0..511)
    const int brow = rt * 64;

    f32x4 acc[2][4];
#pragma unroll
    for (int m = 0; m < 2; ++m)
#pragma unroll
        for (int n = 0; n < 4; ++n) acc[m][n] = (f32x4)(0.0f);

    auto stage = [&](int kt, int buf) {
        // A: 64 rows x 32 f32, 2 glds. LDS dest linear (base + lane*16);
        // SOURCE 16B-chunk pre-swizzled: cg = c ^ (row&7).
#pragma unroll
        for (int i = 0; i < 2; ++i) {
            int chunk = i * 256 + t;
            int rl = chunk >> 3, c = chunk & 7;
            int cg = c ^ (rl & 7);
            const float* g = kv + (size_t)(brow + rl) * D_MODEL + kt * 32 + cg * 4;
            __builtin_amdgcn_global_load_lds(
                (const __attribute__((address_space(1))) void*)g,
                (__attribute__((address_space(3))) void*)
                    ((char*)&Afs[buf][0][0] + i * 4096 + w * 1024),
                16, 0, 0);
        }
        // B: 128 rows x 32 bf16, 2 glds. SOURCE chunk: lc = sc ^ ((row>>1)&3)
        // (kills r13's measured 8-way conflict on the 64B-row fragment read).
#pragma unroll
        for (int i = 0; i < 2; ++i) {
            int chunk = i * 256 + t;
            int rl = chunk >> 2, sc = chunk & 3;
            int lc = sc ^ ((rl >> 1) & 3);
            const short* g = Cw + (size_t)(bx * 128 + rl) * D_MODEL + kt * 32 + lc * 8;
            __builtin_amdgcn_global_load_lds(
                (const __attribute__((address_space(1))) void*)g,
                (__attribute__((address_space(3))) void*)
                    ((char*)&Bsh[buf][0][0] + i * 4096 + w * 1024),
                16, 0, 0);
        }
    };
    auto compute = [&](int buf) {
        short8 af[2], bfr[4];
#pragma unroll
        for (int m = 0; m < 2; ++m) {
            int rl = wr * 32 + m * 16 + r;
            int c0 = (2 * q) ^ (rl & 7);          // swizzled 16B chunks
            int c1 = (2 * q + 1) ^ (rl & 7);
            float4 lo = *(const float4*)&Afs[buf][rl][c0 * 4];
            float4 hi = *(const float4*)&Afs[buf][rl][c1 * 4];
            af[m] = cvt8(lo, hi);                 // pk cvt under MFMA
        }
#pragma unroll
        for (int n = 0; n < 4; ++n) {
            int rl = wc * 64 + n * 16 + r;
            int sc = q ^ ((rl >> 1) & 3);         // swizzled B chunk
            bfr[n] = *reinterpret_cast<const short8*>(&Bsh[buf][rl][sc * 8]);
        }
#pragma unroll
        for (int m = 0; m < 2; ++m)
#pragma unroll
            for (int n = 0; n < 4; ++n)
                acc[m][n] = __builtin_amdgcn_mfma_f32_16x16x32_bf16(
                    af[m], bfr[n], acc[m][n], 0, 0, 0);
    };

    // prologue
    stage(0, 0);
    __syncthreads();
    for (int kt = 0; kt < 32; ++kt) {
        const int cur = kt & 1;
        if (kt < 31) stage(kt + 1, cur ^ 1);   // glds in flight during compute
        compute(cur);
        __syncthreads();                        // one barrier/K-step: drains
    }                                           // glds + covers LDS reuse

    // epilogue: + bo + query residual, f32 store
#pragma unroll
    for (int n = 0; n < 4; ++n) {
        int o = bx * 128 + wc * 64 + n * 16 + r;
        float bov = bo[o];
#pragma unroll
        for (int m = 0; m < 2; ++m) {
            int gb = brow + wr * 32 + m * 16 + q * 4;
#pragma unroll
            for (int j = 0; j < 4; ++j) {
                int grow = gb + j;
                out[(size_t)grow * D_MODEL + o] =
                    acc[m][n][j] + bov +
                    query[(size_t)(grow & (BATCH - 1)) * D_MODEL + o];
            }
        }
    }
}

extern "C" void kernel_launch(void* const* d_in, const int* in_sizes, int n_in,
                              void* d_out, int out_size, void* d_ws, size_t ws_size,
                              hipStream_t stream) {
    // Robust input classification by element count (falls back to dict order):
    int kv_i = 1, q_i = 0, bo_i = 6;
    int w_i[4] = {2, 3, 4, 5};
    int nw = 0;
    for (int i = 0; i < n_in; ++i) {
        long s = in_sizes[i];
        if (s == 33554432) kv_i = i;
        else if (s == 4194304) q_i = i;
        else if (s == 1024) bo_i = i;
        else if (s == 1048576 && nw < 4) w_i[nw++] = i;
    }
    const float* query = (const float*)d_in[q_i];
    const float* kv    = (const float*)d_in[kv_i];
    const float* Wv    = (const float*)d_in[w_i[2]];
    const float* Wo    = (const float*)d_in[w_i[3]];
    const float* bo    = (const float*)d_in[bo_i];
    short* Cw  = (short*)d_ws;              // 1024*1024 bf16 = 2 MB
    float* out = (float*)d_out;             // f32 output

    fuse_w_kernel<<<dim3(16, 16), dim3(256), 0, stream>>>(Wo, Wv, Cw);
    attn_gemm_kernel<<<dim3(4096), dim3(256), 0, stream>>>(kv, query, Cw, bo, out);
}

// Round 15
// 175.698 us; speedup vs baseline: 1.2014x; 1.2014x over previous
//
#include <hip/hip_runtime.h>
#include <hip/hip_bf16.h>

// out[m,b,:] = kv[m,b,:] @ W + bo + query[b,:],  W = (Wo@Wv) row o, col d
// (softmax over size-1 axis == 1 -> ones; q/k/Wq/Wk dead). f32 output.
// K1: Cw = Wo@Wv, MFMA bf16, 64x64 tiles, 256 blocks (~3us, proven r9).
// K2: r13 base + BK=64 (16 K-steps: halves barrier-latency exposures, the
//     cost that r7-r14 shows scales) + XOR-swizzled A AND B tiles
//     (conflict-free by bank algebra; B-swizzle isolated-good in r14).
//     Single-buffered 32 KB LDS -> ~5 blocks/CU overlap preserved.

typedef __attribute__((ext_vector_type(4))) float f32x4;
typedef __attribute__((ext_vector_type(8))) short short8;

#define D_MODEL 1024
#define BATCH   4096
#define M_ROWS  32768   // 8 * 4096

__device__ __forceinline__ short f2bf(float f) {
    union { float f; unsigned u; } x; x.f = f;
    unsigned r = (x.u + 0x7fffu + ((x.u >> 16) & 1u)) >> 16;   // RNE
    return (short)r;
}

__device__ __forceinline__ unsigned bfpk(float lo, float hi) {
    __hip_bfloat162 h = __float22bfloat162_rn(make_float2(lo, hi));  // v_cvt_pk_bf16_f32
    unsigned u; __builtin_memcpy(&u, &h, 4); return u;
}

__device__ __forceinline__ short8 cvt8(float4 a, float4 b) {
    union { unsigned u[4]; short8 s; } r;
    r.u[0] = bfpk(a.x, a.y);
    r.u[1] = bfpk(a.z, a.w);
    r.u[2] = bfpk(b.x, b.y);
    r.u[3] = bfpk(b.z, b.w);
    return r.s;
}

// ---------------- Kernel 1: fuse weights Cw = Wo @ Wv (bf16, MFMA, 64x64) ----------------
__global__ __launch_bounds__(256) void fuse_w_kernel(
        const float* __restrict__ Wo, const float* __restrict__ Wv,
        short* __restrict__ Cw) {
    __shared__ __align__(16) short Ash[64][32];   // Wo tile  [o][e]
    __shared__ __align__(16) short Bsh[64][32];   // Wv tile transposed: [d][e]
    const int t = threadIdx.x;
    const int lane = t & 63;
    const int w = t >> 6;
    const int wr = w >> 1, wc = w & 1;
    const int brow = blockIdx.y * 64;   // o
    const int bcol = blockIdx.x * 64;   // d

    f32x4 acc[2][2];
#pragma unroll
    for (int m = 0; m < 2; ++m)
#pragma unroll
        for (int n = 0; n < 2; ++n) acc[m][n] = (f32x4)(0.0f);

    for (int kt = 0; kt < 32; ++kt) {
        const float* ga = Wo + (size_t)(brow + (t >> 2)) * D_MODEL + kt * 32 + (t & 3) * 8;
        float4 a0 = *(const float4*)ga;
        float4 a1 = *(const float4*)(ga + 4);
        float4 bv[2];
#pragma unroll
        for (int j = 0; j < 2; ++j) {
            int lin = j * 256 + t;
            int e = lin >> 4, c4 = lin & 15;
            bv[j] = *(const float4*)(Wv + (size_t)(kt * 32 + e) * D_MODEL + bcol + c4 * 4);
        }
        *reinterpret_cast<short8*>(&Ash[t >> 2][(t & 3) * 8]) = cvt8(a0, a1);
#pragma unroll
        for (int j = 0; j < 2; ++j) {
            int lin = j * 256 + t;
            int e = lin >> 4, c4 = lin & 15;
            int d = c4 * 4;
            Bsh[d + 0][e] = f2bf(bv[j].x);
            Bsh[d + 1][e] = f2bf(bv[j].y);
            Bsh[d + 2][e] = f2bf(bv[j].z);
            Bsh[d + 3][e] = f2bf(bv[j].w);
        }
        __syncthreads();
        {
            const int r = lane & 15, q = lane >> 4;
            short8 af[2], bfr[2];
#pragma unroll
            for (int m = 0; m < 2; ++m)
                af[m] = *reinterpret_cast<const short8*>(&Ash[wr * 32 + m * 16 + r][q * 8]);
#pragma unroll
            for (int n = 0; n < 2; ++n)
                bfr[n] = *reinterpret_cast<const short8*>(&Bsh[wc * 32 + n * 16 + r][q * 8]);
#pragma unroll
            for (int m = 0; m < 2; ++m)
#pragma unroll
                for (int n = 0; n < 2; ++n)
                    acc[m][n] = __builtin_amdgcn_mfma_f32_16x16x32_bf16(
                        af[m], bfr[n], acc[m][n], 0, 0, 0);
        }
        __syncthreads();
    }

    const int r = lane & 15, q = lane >> 4;
#pragma unroll
    for (int m = 0; m < 2; ++m)
#pragma unroll
        for (int n = 0; n < 2; ++n)
#pragma unroll
            for (int j = 0; j < 4; ++j) {
                int o = brow + wr * 32 + m * 16 + q * 4 + j;     // C/D: row=(l>>4)*4+j
                int d = bcol + wc * 32 + n * 16 + r;             //      col=l&15
                Cw[(size_t)o * D_MODEL + d] = f2bf(acc[m][n][j]);
            }
}

// ---------------- Kernel 2: out = kv @ Cw.T + bo + query — BK=64, swizzled, 2-barrier ----------------
__global__ __launch_bounds__(256, 4) void attn_gemm_kernel(
        const float* __restrict__ kv, const float* __restrict__ query,
        const short* __restrict__ Cw, const float* __restrict__ bo,
        float* __restrict__ out) {
    // A: 64 rows x 64 f32 (256B row = 16 chunks of 16B), XOR-swizzled.
    // B: 128 rows x 64 bf16 (128B row = 8 chunks), XOR-swizzled.
    // Both: LDS[row][d] holds global chunk d^(row&7); read chunk c at
    // position c^(row&7). glds dest linear, SOURCE pre-swizzled (rule #21).
    __shared__ __align__(16) float Afs[64][64];    // 16 KB
    __shared__ __align__(16) short Bsh[128][64];   // 16 KB
    const int t = threadIdx.x;
    const int lane = t & 63;
    const int w = t >> 6;
    const int wr = w >> 1, wc = w & 1;
    const int r = lane & 15, q = lane >> 4;

    // XCD swizzle: XCD = L % 8; 8 o-tiles of one row-tile share an XCD ->
    // kv L2-reused 8x (proven r8: FETCH 574->141 MB).
    const int L = blockIdx.x;
    const int x = L & 7, j5 = L >> 3;
    const int bx = j5 & 7;                   // o-tile (0..7)
    const int rt = (j5 >> 3) * 8 + x;        // row-tile (0..511)
    const int brow = rt * 64;

    f32x4 acc[2][4];
#pragma unroll
    for (int m = 0; m < 2; ++m)
#pragma unroll
        for (int n = 0; n < 4; ++n) acc[m][n] = (f32x4)(0.0f);

    for (int kt = 0; kt < 16; ++kt) {
        // ---- stage A: 16 KB = 4 glds issues. chunk=i*256+t; row=chunk>>4,
        //      dest chunk d=chunk&15; source chunk cs = d^(row&7).
#pragma unroll
        for (int i = 0; i < 4; ++i) {
            int chunk = i * 256 + t;
            int rl = chunk >> 4, d = chunk & 15;
            int cs = d ^ (rl & 7);
            const float* g = kv + (size_t)(brow + rl) * D_MODEL + kt * 64 + cs * 4;
            __builtin_amdgcn_global_load_lds(
                (const __attribute__((address_space(1))) void*)g,
                (__attribute__((address_space(3))) void*)
                    ((char*)&Afs[0][0] + i * 4096 + w * 1024),
                16, 0, 0);
        }
        // ---- stage B: 16 KB = 4 glds issues. row=chunk>>3, d=chunk&7,
        //      cs = d^(row&7).
#pragma unroll
        for (int i = 0; i < 4; ++i) {
            int chunk = i * 256 + t;
            int rl = chunk >> 3, d = chunk & 7;
            int cs = d ^ (rl & 7);
            const short* g = Cw + (size_t)(bx * 128 + rl) * D_MODEL + kt * 64 + cs * 8;
            __builtin_amdgcn_global_load_lds(
                (const __attribute__((address_space(1))) void*)g,
                (__attribute__((address_space(3))) void*)
                    ((char*)&Bsh[0][0] + i * 4096 + w * 1024),
                16, 0, 0);
        }
        __syncthreads();   // glds drained (implicit vmcnt), LDS valid
#pragma unroll
        for (int s = 0; s < 2; ++s) {
            short8 af[2], bfr[4];
#pragma unroll
            for (int m = 0; m < 2; ++m) {
                int row = wr * 32 + m * 16 + r;
                int c0 = (s * 8 + q * 2) ^ (row & 7);
                int c1 = (s * 8 + q * 2 + 1) ^ (row & 7);
                float4 lo = *(const float4*)&Afs[row][c0 * 4];
                float4 hi = *(const float4*)&Afs[row][c1 * 4];
                af[m] = cvt8(lo, hi);                 // pk cvt under MFMA
            }
#pragma unroll
            for (int n = 0; n < 4; ++n) {
                int row = wc * 64 + n * 16 + r;
                int c = (s * 4 + q) ^ (row & 7);
                bfr[n] = *reinterpret_cast<const short8*>(&Bsh[row][c * 8]);
            }
#pragma unroll
            for (int m = 0; m < 2; ++m)
#pragma unroll
                for (int n = 0; n < 4; ++n)
                    acc[m][n] = __builtin_amdgcn_mfma_f32_16x16x32_bf16(
                        af[m], bfr[n], acc[m][n], 0, 0, 0);
        }
        __syncthreads();
    }

    // epilogue: + bo + query residual, f32 store
#pragma unroll
    for (int n = 0; n < 4; ++n) {
        int o = bx * 128 + wc * 64 + n * 16 + r;
        float bov = bo[o];
#pragma unroll
        for (int m = 0; m < 2; ++m) {
            int gb = brow + wr * 32 + m * 16 + q * 4;
#pragma unroll
            for (int j = 0; j < 4; ++j) {
                int grow = gb + j;
                out[(size_t)grow * D_MODEL + o] =
                    acc[m][n][j] + bov +
                    query[(size_t)(grow & (BATCH - 1)) * D_MODEL + o];
            }
        }
    }
}

extern "C" void kernel_launch(void* const* d_in, const int* in_sizes, int n_in,
                              void* d_out, int out_size, void* d_ws, size_t ws_size,
                              hipStream_t stream) {
    // Robust input classification by element count (falls back to dict order):
    int kv_i = 1, q_i = 0, bo_i = 6;
    int w_i[4] = {2, 3, 4, 5};
    int nw = 0;
    for (int i = 0; i < n_in; ++i) {
        long s = in_sizes[i];
        if (s == 33554432) kv_i = i;
        else if (s == 4194304) q_i = i;
        else if (s == 1024) bo_i = i;
        else if (s == 1048576 && nw < 4) w_i[nw++] = i;
    }
    const float* query = (const float*)d_in[q_i];
    const float* kv    = (const float*)d_in[kv_i];
    const float* Wv    = (const float*)d_in[w_i[2]];
    const float* Wo    = (const float*)d_in[w_i[3]];
    const float* bo    = (const float*)d_in[bo_i];
    short* Cw  = (short*)d_ws;              // 1024*1024 bf16 = 2 MB
    float* out = (float*)d_out;             // f32 output

    fuse_w_kernel<<<dim3(16, 16), dim3(256), 0, stream>>>(Wo, Wv, Cw);
    attn_gemm_kernel<<<dim3(4096), dim3(256), 0, stream>>>(kv, query, Cw, bo, out);
}